// Round 5
// baseline (460.845 us; speedup 1.0000x reference)
//
#include <hip/hip_runtime.h>
#include <math.h>

// ---------------------------------------------------------------------------
// out[b][s] = <v_b| I_{2^s} (x) W (x) I |v_b> / <v_b|v_b>,  s=0..12
// Q_s = <W, G_s>, Gram via MFMA fp16 (RNE), fp32 accum.
// R5: persistent blocks, software-pipelined. Each block owns 2 contiguous
// tile-units (s=3..11 + sumsq; buffer A) and 2 col tile-units (s=0,1,2,12;
// buffer B), staging unit j+1's global loads during unit j's compute.
// Unit math identical to R4 (verified).
// ws layout (floats): [0..256) W row-major; [256..) acc[row*14+s], slot13=sumsq
// ---------------------------------------------------------------------------

typedef _Float16 f16x8 __attribute__((ext_vector_type(8)));
typedef float f32x4 __attribute__((ext_vector_type(4)));
typedef float f32x16 __attribute__((ext_vector_type(16)));
#define MFMAH(a, b, c) __builtin_amdgcn_mfma_f32_16x16x32_f16((a), (b), (c), 0, 0, 0)
#define MFMA32(a, b, c) __builtin_amdgcn_mfma_f32_32x32x16_f16((a), (b), (c), 0, 0, 0)

union H4 { _Float16 h[4]; uint2 q; };
union Frag { _Float16 h[8]; f16x8 v; uint2 q[2]; unsigned int w[4]; };

__device__ __forceinline__ int swz(int g) { return g ^ (g >> 5); }

__device__ __forceinline__ float wave_sum(float x) {
    #pragma unroll
    for (int off = 32; off > 0; off >>= 1) x += __shfl_down(x, off, 64);
    return x;
}

// ------------------------- setup: build W on device -------------------------
using c2 = float2;
__device__ __forceinline__ c2 cmul(c2 a, c2 b) {
    return make_float2(a.x * b.x - a.y * b.y, a.x * b.y + a.y * b.x);
}
__device__ __forceinline__ c2 cadd(c2 a, c2 b) { return make_float2(a.x + b.x, a.y + b.y); }

__device__ __forceinline__ c2 kelem(const c2 u[4][2][2], int i, int j) {
    c2 p = cmul(u[0][(i >> 3) & 1][(j >> 3) & 1], u[1][(i >> 2) & 1][(j >> 2) & 1]);
    p = cmul(p, u[2][(i >> 1) & 1][(j >> 1) & 1]);
    p = cmul(p, u[3][i & 1][j & 1]);
    return p;
}
__device__ __forceinline__ int fperm(int x) {
    int b3 = (x >> 3) & 1, b2 = (x >> 2) & 1, b1 = (x >> 1) & 1, b0 = x & 1;
    b2 ^= b3; b1 ^= b2; b0 ^= b1; b3 ^= b0;
    return (b3 << 3) | (b2 << 2) | (b1 << 1) | b0;
}

__global__ __launch_bounds__(256) void setup_kernel(const float* __restrict__ weight,
                                                    float* __restrict__ ws) {
    __shared__ c2 ush[3][4][2][2];
    __shared__ c2 A[256], B[256];
    const int t = threadIdx.x;

    if (t < 12) {
        const int r = t / 4, q = t % 4;
        const float a = weight[12 * r + 3 * q + 0];
        const float b = weight[12 * r + 3 * q + 1];
        const float c = weight[12 * r + 3 * q + 2];
        const float ca = cosf(0.5f * a), sa = sinf(0.5f * a);
        const float cc = cosf(0.5f * c), sc = sinf(0.5f * c);
        const c2 e = make_float2(cosf(0.5f * b), -sinf(0.5f * b));
        const c2 eb = make_float2(e.x, -e.y);
        ush[r][q][0][0] = make_float2(cc * ca * e.x - sc * sa * eb.x, cc * ca * e.y - sc * sa * eb.y);
        ush[r][q][0][1] = make_float2(-cc * sa * e.x - sc * ca * eb.x, -cc * sa * e.y - sc * ca * eb.y);
        ush[r][q][1][0] = make_float2(sc * ca * e.x + cc * sa * eb.x, sc * ca * e.y + cc * sa * eb.y);
        ush[r][q][1][1] = make_float2(-sc * sa * e.x + cc * ca * eb.x, -sc * sa * e.y + cc * ca * eb.y);
    }
    __syncthreads();

    const int i = t >> 4, j = t & 15;
    A[t] = kelem(ush[0], i, j);
    __syncthreads();
    B[fperm(i) * 16 + j] = A[t];
    __syncthreads();
    {
        c2 acc = make_float2(0.f, 0.f);
        #pragma unroll
        for (int k = 0; k < 16; ++k) acc = cadd(acc, cmul(kelem(ush[1], i, k), B[k * 16 + j]));
        __syncthreads();
        A[t] = acc;
    }
    __syncthreads();
    B[fperm(i) * 16 + j] = A[t];
    __syncthreads();
    {
        c2 acc = make_float2(0.f, 0.f);
        #pragma unroll
        for (int k = 0; k < 16; ++k) acc = cadd(acc, cmul(kelem(ush[2], i, k), B[k * 16 + j]));
        __syncthreads();
        A[t] = acc;
    }
    __syncthreads();
    {
        float wr = 0.f;
        #pragma unroll
        for (int k = 0; k < 16; ++k) {
            const c2 a = A[k * 16 + i];
            const c2 b = A[(k ^ 15) * 16 + j];
            wr += a.x * b.x + a.y * b.y;
        }
        ws[t] = wr;
    }
    for (int z = t; z < 512 * 14; z += 256) ws[256 + z] = 0.f;
}

// ----------------------------- unit helpers ---------------------------------

__device__ __forceinline__ void contract16(const float* __restrict__ Wl, const f32x4& acc,
                                           int i, int h, int l, float* dst) {
    const float4 wr = *(const float4*)&Wl[(i << 4) + (h << 2)];
    float q = wr.x * acc[0] + wr.y * acc[1] + wr.z * acc[2] + wr.w * acc[3];
    q = wave_sum(q);
    if (l == 0) atomicAdd(dst, q);
}

// Paired starts (S, S+1), S in {3,5,7}: one 32x32x16 Gram over J = bits
// (11-S..15-S). C/D: col = lane&31, row = (reg&3)+8*(reg>>2)+4*(lane>>5).
template <int S>
__device__ __forceinline__ void pair_unit(const unsigned short* __restrict__ sh16,
                                          const float* __restrict__ Wl,
                                          int l, float* accrow) {
    const int Jp = l & 31, h2 = l >> 5;
    f32x16 acc = {0.f, 0.f, 0.f, 0.f, 0.f, 0.f, 0.f, 0.f,
                  0.f, 0.f, 0.f, 0.f, 0.f, 0.f, 0.f, 0.f};
    #pragma unroll
    for (int cc = 0; cc < 16; ++cc) {
        int e0;
        if (S == 3)      e0 = (Jp << 8) + (cc << 4) + (h2 << 3);
        else if (S == 5) e0 = ((cc >> 2) << 11) + (Jp << 6) + ((cc & 3) << 4) + (h2 << 3);
        else             e0 = (cc << 9) + (Jp << 4) + (h2 << 3);
        const f16x8 f = *(const f16x8*)&sh16[swz(e0 >> 3) << 3];
        acc = MFMA32(f, f, acc);
    }
    float qa = 0.f, qb = 0.f;
    #pragma unroll
    for (int r2 = 0; r2 < 8; ++r2) {
        const int r = 2 * r2;
        const int J = (r & 3) + 8 * (r >> 2) + 4 * h2;
        const float w = Wl[((J >> 1) << 4) + (Jp >> 1)];
        qa += w * ((Jp & 1) ? acc[r + 1] : acc[r]);
    }
    #pragma unroll
    for (int r = 0; r < 8; ++r) {
        const int J = (r & 3) + 8 * (r >> 2) + 4 * h2;
        const float w = Wl[((J & 15) << 4) + (Jp & 15)];
        qb += w * ((Jp & 16) ? acc[r + 8] : acc[r]);
    }
    qa = wave_sum(qa);
    qb = wave_sum(qb);
    if (l == 0) { atomicAdd(&accrow[S], qa); atomicAdd(&accrow[S + 1], qb); }
}

__device__ __forceinline__ void unit9(const unsigned short* __restrict__ sh16,
                                      const float* __restrict__ Wl,
                                      int i, int h, int l, float* accrow) {
    f32x4 acc = {0.f, 0.f, 0.f, 0.f};
    #pragma unroll
    for (int cc = 0; cc < 16; ++cc) {
        const int e0 = ((4 * cc + h) << 7) + (i << 3);
        const f16x8 f = *(const f16x8*)&sh16[swz(e0 >> 3) << 3];
        acc = MFMAH(f, f, acc);
    }
    contract16(Wl, acc, i, h, l, &accrow[9]);
}

__device__ __forceinline__ void unit10(const unsigned short* __restrict__ sh16,
                                       const float* __restrict__ Wl,
                                       int i, int h, int l, int c0, int c1, float* accrow) {
    f32x4 acc = {0.f, 0.f, 0.f, 0.f};
    #pragma unroll
    for (int cc = c0; cc < c1; ++cc) {
        const int a0 = 8 * cc + 2 * h;
        const int ea = a0 * 64 + 4 * i;
        const int eb = ea + 64;
        Frag fr;
        fr.q[0] = *(const uint2*)&sh16[(swz(ea >> 3) << 3) + (ea & 7)];
        fr.q[1] = *(const uint2*)&sh16[(swz(eb >> 3) << 3) + (eb & 7)];
        acc = MFMAH(fr.v, fr.v, acc);
    }
    contract16(Wl, acc, i, h, l, &accrow[10]);
}

__device__ __forceinline__ void unit11(const unsigned short* __restrict__ sh16,
                                       const float* __restrict__ Wl,
                                       int i, int h, int l, int c0, int c1, float* accrow) {
    f32x4 acc = {0.f, 0.f, 0.f, 0.f};
    #pragma unroll
    for (int cc = c0; cc < c1; ++cc) {
        Frag fr;
        #pragma unroll
        for (int p = 0; p < 4; ++p) {
            const int ap = 16 * cc + 4 * h + p;
            const int e = ap * 32 + 2 * i;
            fr.w[p] = *(const unsigned int*)&sh16[(swz(e >> 3) << 3) + (e & 7)];
        }
        acc = MFMAH(fr.v, fr.v, acc);
    }
    contract16(Wl, acc, i, h, l, &accrow[11]);
}

// --------------------------- pipeline stage funcs ---------------------------

__device__ __forceinline__ void load_contig(const float* __restrict__ v, int cu, int t,
                                            float4 (&rc)[8]) {
    const float4* b4 = (const float4*)(v + ((size_t)(cu >> 3) << 16) + ((cu & 7) << 13));
    #pragma unroll
    for (int m = 0; m < 8; ++m) rc[m] = b4[m * 256 + t];
}

__device__ __forceinline__ void store_contig(const float4 (&rc)[8],
                                             unsigned short* __restrict__ sh,
                                             int t, int l, float* accrow) {
    float ss = 0.f;
    #pragma unroll
    for (int m = 0; m < 8; ++m) {
        const float4 d = rc[m];
        ss = fmaf(d.x, d.x, ss); ss = fmaf(d.y, d.y, ss);
        ss = fmaf(d.z, d.z, ss); ss = fmaf(d.w, d.w, ss);
        H4 p;
        p.h[0] = (_Float16)d.x; p.h[1] = (_Float16)d.y;
        p.h[2] = (_Float16)d.z; p.h[3] = (_Float16)d.w;
        const int e0 = (m * 256 + t) * 4;
        const int idx = (swz(e0 >> 3) << 3) + (e0 & 7);
        *(uint2*)&sh[idx] = p.q;
    }
    const float s2 = wave_sum(ss);
    if (l == 0) atomicAdd(&accrow[13], s2);
}

__device__ __forceinline__ void load_col(const float* __restrict__ v, int du, int l, int wv,
                                         float (&rl)[32]) {
    const float* bp = v + ((size_t)(du >> 3) << 16) + ((du & 7) << 6) + l;
    #pragma unroll
    for (int q = 0; q < 32; ++q) rl[q] = bp[(32 * wv + q) * 512];
}

__device__ __forceinline__ void store_col(const float (&rl)[32],
                                          unsigned short* __restrict__ sh,
                                          int l, int wv) {
    #pragma unroll
    for (int m = 0; m < 8; ++m) {
        const int u0 = 32 * wv + 4 * m;
        H4 p;
        p.h[0] = (_Float16)rl[4 * m + 0];
        p.h[1] = (_Float16)rl[4 * m + 1];
        p.h[2] = (_Float16)rl[4 * m + 2];
        p.h[3] = (_Float16)rl[4 * m + 3];
        *(uint2*)&sh[l * 128 + (u0 ^ (8 * (l & 15)))] = p.q;
    }
}

__device__ __forceinline__ void compute_contig(const unsigned short* __restrict__ sh,
                                               const float* __restrict__ Wl,
                                               int wv, int i, int h, int l, float* accrow) {
    if (wv == 0) {
        pair_unit<3>(sh, Wl, l, accrow);
        unit10(sh, Wl, i, h, l, 0, 8, accrow);
    } else if (wv == 1) {
        pair_unit<5>(sh, Wl, l, accrow);
        unit10(sh, Wl, i, h, l, 8, 16, accrow);
    } else if (wv == 2) {
        pair_unit<7>(sh, Wl, l, accrow);
        unit11(sh, Wl, i, h, l, 0, 8, accrow);
    } else {
        unit9(sh, Wl, i, h, l, accrow);
        unit11(sh, Wl, i, h, l, 8, 16, accrow);
    }
}

__device__ __forceinline__ void compute_col(const unsigned short* __restrict__ sh,
                                            const float* __restrict__ Wl,
                                            int wv, int i, int h, int l, float* accrow) {
    if (wv == 0) {          // s=0
        f32x4 acc = {0.f, 0.f, 0.f, 0.f};
        #pragma unroll
        for (int cc = 0; cc < 16; ++cc) {
            const int cl = 4 * cc + h;
            const f16x8 f = *(const f16x8*)&sh[cl * 128 + ((8 * i) ^ (8 * (cl & 15)))];
            acc = MFMAH(f, f, acc);
        }
        contract16(Wl, acc, i, h, l, &accrow[0]);
    } else if (wv == 1) {   // s=1 full + s=2 tail
        {
            f32x4 acc = {0.f, 0.f, 0.f, 0.f};
            #pragma unroll
            for (int cc = 0; cc < 16; ++cc) {
                const int cl = 4 * cc + h;
                const int k = 8 * (cl & 15);
                Frag fr;
                fr.q[0] = *(const uint2*)&sh[cl * 128 + ((4 * i) ^ k)];
                fr.q[1] = *(const uint2*)&sh[cl * 128 + ((64 + 4 * i) ^ k)];
                acc = MFMAH(fr.v, fr.v, acc);
            }
            contract16(Wl, acc, i, h, l, &accrow[1]);
        }
        {
            f32x4 acc = {0.f, 0.f, 0.f, 0.f};
            #pragma unroll
            for (int cc = 12; cc < 16; ++cc) {
                const int cl = 4 * cc + h;
                const int k = 8 * (cl & 15);
                Frag fr;
                #pragma unroll
                for (int p = 0; p < 4; ++p)
                    fr.w[p] = *(const unsigned int*)&sh[cl * 128 + ((2 * i + 32 * p) ^ k)];
                acc = MFMAH(fr.v, fr.v, acc);
            }
            contract16(Wl, acc, i, h, l, &accrow[2]);
        }
    } else if (wv == 2) {   // s=2 head
        f32x4 acc = {0.f, 0.f, 0.f, 0.f};
        #pragma unroll
        for (int cc = 0; cc < 12; ++cc) {
            const int cl = 4 * cc + h;
            const int k = 8 * (cl & 15);
            Frag fr;
            #pragma unroll
            for (int p = 0; p < 4; ++p)
                fr.w[p] = *(const unsigned int*)&sh[cl * 128 + ((2 * i + 32 * p) ^ k)];
            acc = MFMAH(fr.v, fr.v, acc);
        }
        contract16(Wl, acc, i, h, l, &accrow[2]);
    } else {                // s=12
        f32x4 acc = {0.f, 0.f, 0.f, 0.f};
        #pragma unroll
        for (int cc = 0; cc < 16; ++cc) {
            const int k0 = 32 * cc + 8 * h;
            const int cg = k0 >> 7, u0 = k0 & 127;
            const int col = 16 * cg + i;
            const f16x8 f = *(const f16x8*)&sh[col * 128 + (u0 ^ (8 * i))];
            acc = MFMAH(f, f, acc);
        }
        contract16(Wl, acc, i, h, l, &accrow[12]);
    }
}

// ------------------------------ fused main ----------------------------------
// 2048 persistent blocks; block b owns contig units {2b, 2b+1} (buffer A) and
// col units {2b, 2b+1} (buffer B). Pipeline: next unit's global loads issue
// before current unit's compute; one LDS buffer per family (no aliasing).
__global__ __launch_bounds__(256, 4) void main_kernel(const float* __restrict__ v,
                                                      const float* __restrict__ ws,
                                                      float* __restrict__ accg) {
    __shared__ unsigned short shA[8192];   // contig tile
    __shared__ unsigned short shB[8192];   // col tile
    __shared__ float Wl[256];
    const int t = threadIdx.x;
    const int l = t & 63, wv = t >> 6;
    const int i = l & 15, h = l >> 4;
    Wl[t] = ws[t];

    const int b = blockIdx.x;
    float4 rc[8];
    float rl[32];

    // prologue: stage contig unit 2b
    load_contig(v, 2 * b, t, rc);
    store_contig(rc, shA, t, l, &accg[((2 * b) >> 3) * 14]);
    __syncthreads();

    #pragma unroll
    for (int p = 0; p < 2; ++p) {
        const int cu = 2 * b + p;          // contig unit currently in shA
        const int du = 2 * b + p;          // col unit this iteration
        load_col(v, du, l, wv, rl);                                // prefetch
        compute_contig(shA, Wl, wv, i, h, l, &accg[(cu >> 3) * 14]);
        store_col(rl, shB, l, wv);
        __syncthreads();
        if (p == 0) load_contig(v, 2 * b + 1, t, rc);              // prefetch
        compute_col(shB, Wl, wv, i, h, l, &accg[(du >> 3) * 14]);
        if (p == 0) store_contig(rc, shA, t, l, &accg[((2 * b + 1) >> 3) * 14]);
        __syncthreads();
    }
}

__global__ __launch_bounds__(256) void finalize_kernel(const float* __restrict__ acc,
                                                       float* __restrict__ out) {
    const int idx = blockIdx.x * 256 + threadIdx.x;
    if (idx < 512 * 13) {
        const int row = idx / 13, s = idx % 13;
        out[idx] = acc[row * 14 + s] / acc[row * 14 + 13];
    }
}

extern "C" void kernel_launch(void* const* d_in, const int* in_sizes, int n_in,
                              void* d_out, int out_size, void* d_ws, size_t ws_size,
                              hipStream_t stream) {
    const float* vb = (const float*)d_in[0];
    const float* wt = (const float*)d_in[1];
    float* out = (float*)d_out;
    float* ws = (float*)d_ws;
    float* acc = ws + 256;

    setup_kernel<<<1, 256, 0, stream>>>(wt, ws);
    main_kernel<<<2048, 256, 0, stream>>>(vb, ws, acc);
    finalize_kernel<<<26, 256, 0, stream>>>(acc, out);
}

// Round 6
// 194.596 us; speedup vs baseline: 2.3682x; 2.3682x over previous
//
#include <hip/hip_runtime.h>
#include <math.h>

// ---------------------------------------------------------------------------
// out[b][s] = <v_b| I_{2^s} (x) W (x) I |v_b> / <v_b|v_b>,  s=0..12
// Q_s = <W, G_s>, Gram via MFMA fp16 (RNE), fp32 accum.  (R4 structure.)
// Contiguous path (8192-elem tiles, bits 0..12): s=3..11 + sumsq, s-pairs
// (3,4),(5,6),(7,8) fused via 32x32x16 Gram (window-union = 5 bits).
// Col path (128u x 64c tiles, u = bits 9..15): s=0,1,2,12.
// R6: blockIdx remap so all 16 blocks of one row share idx%8 (same XCD under
// round-robin dispatch) and dispatch adjacently -> col pass re-reads the row
// from that XCD's L2 instead of L3/HBM.
// ws layout (floats): [0..256) W row-major; [256..) acc[row*14+s], slot13=sumsq
// ---------------------------------------------------------------------------

typedef _Float16 f16x8 __attribute__((ext_vector_type(8)));
typedef float f32x4 __attribute__((ext_vector_type(4)));
typedef float f32x16 __attribute__((ext_vector_type(16)));
#define MFMAH(a, b, c) __builtin_amdgcn_mfma_f32_16x16x32_f16((a), (b), (c), 0, 0, 0)
#define MFMA32(a, b, c) __builtin_amdgcn_mfma_f32_32x32x16_f16((a), (b), (c), 0, 0, 0)

union H4 { _Float16 h[4]; uint2 q; };
union Frag { _Float16 h[8]; f16x8 v; uint2 q[2]; unsigned int w[4]; };

__device__ __forceinline__ int swz(int g) { return g ^ (g >> 5); }

__device__ __forceinline__ float wave_sum(float x) {
    #pragma unroll
    for (int off = 32; off > 0; off >>= 1) x += __shfl_down(x, off, 64);
    return x;
}

// ------------------------- setup: build W on device -------------------------
using c2 = float2;
__device__ __forceinline__ c2 cmul(c2 a, c2 b) {
    return make_float2(a.x * b.x - a.y * b.y, a.x * b.y + a.y * b.x);
}
__device__ __forceinline__ c2 cadd(c2 a, c2 b) { return make_float2(a.x + b.x, a.y + b.y); }

__device__ __forceinline__ c2 kelem(const c2 u[4][2][2], int i, int j) {
    c2 p = cmul(u[0][(i >> 3) & 1][(j >> 3) & 1], u[1][(i >> 2) & 1][(j >> 2) & 1]);
    p = cmul(p, u[2][(i >> 1) & 1][(j >> 1) & 1]);
    p = cmul(p, u[3][i & 1][j & 1]);
    return p;
}
__device__ __forceinline__ int fperm(int x) {
    int b3 = (x >> 3) & 1, b2 = (x >> 2) & 1, b1 = (x >> 1) & 1, b0 = x & 1;
    b2 ^= b3; b1 ^= b2; b0 ^= b1; b3 ^= b0;
    return (b3 << 3) | (b2 << 2) | (b1 << 1) | b0;
}

__global__ __launch_bounds__(256) void setup_kernel(const float* __restrict__ weight,
                                                    float* __restrict__ ws) {
    __shared__ c2 ush[3][4][2][2];
    __shared__ c2 A[256], B[256];
    const int t = threadIdx.x;

    if (t < 12) {
        const int r = t / 4, q = t % 4;
        const float a = weight[12 * r + 3 * q + 0];
        const float b = weight[12 * r + 3 * q + 1];
        const float c = weight[12 * r + 3 * q + 2];
        const float ca = cosf(0.5f * a), sa = sinf(0.5f * a);
        const float cc = cosf(0.5f * c), sc = sinf(0.5f * c);
        const c2 e = make_float2(cosf(0.5f * b), -sinf(0.5f * b));
        const c2 eb = make_float2(e.x, -e.y);
        ush[r][q][0][0] = make_float2(cc * ca * e.x - sc * sa * eb.x, cc * ca * e.y - sc * sa * eb.y);
        ush[r][q][0][1] = make_float2(-cc * sa * e.x - sc * ca * eb.x, -cc * sa * e.y - sc * ca * eb.y);
        ush[r][q][1][0] = make_float2(sc * ca * e.x + cc * sa * eb.x, sc * ca * e.y + cc * sa * eb.y);
        ush[r][q][1][1] = make_float2(-sc * sa * e.x + cc * ca * eb.x, -sc * sa * e.y + cc * ca * eb.y);
    }
    __syncthreads();

    const int i = t >> 4, j = t & 15;
    A[t] = kelem(ush[0], i, j);
    __syncthreads();
    B[fperm(i) * 16 + j] = A[t];
    __syncthreads();
    {
        c2 acc = make_float2(0.f, 0.f);
        #pragma unroll
        for (int k = 0; k < 16; ++k) acc = cadd(acc, cmul(kelem(ush[1], i, k), B[k * 16 + j]));
        __syncthreads();
        A[t] = acc;
    }
    __syncthreads();
    B[fperm(i) * 16 + j] = A[t];
    __syncthreads();
    {
        c2 acc = make_float2(0.f, 0.f);
        #pragma unroll
        for (int k = 0; k < 16; ++k) acc = cadd(acc, cmul(kelem(ush[2], i, k), B[k * 16 + j]));
        __syncthreads();
        A[t] = acc;
    }
    __syncthreads();
    {
        float wr = 0.f;
        #pragma unroll
        for (int k = 0; k < 16; ++k) {
            const c2 a = A[k * 16 + i];
            const c2 b = A[(k ^ 15) * 16 + j];
            wr += a.x * b.x + a.y * b.y;
        }
        ws[t] = wr;
    }
    for (int z = t; z < 512 * 14; z += 256) ws[256 + z] = 0.f;
}

// ----------------------------- unit helpers ---------------------------------

__device__ __forceinline__ void contract16(const float* __restrict__ Wl, const f32x4& acc,
                                           int i, int h, int l, float* dst) {
    const float4 wr = *(const float4*)&Wl[(i << 4) + (h << 2)];
    float q = wr.x * acc[0] + wr.y * acc[1] + wr.z * acc[2] + wr.w * acc[3];
    q = wave_sum(q);
    if (l == 0) atomicAdd(dst, q);
}

// Paired starts (S, S+1), S in {3,5,7}: one 32x32x16 Gram over J = bits
// (11-S..15-S). C/D: col = lane&31, row = (reg&3)+8*(reg>>2)+4*(lane>>5).
template <int S>
__device__ __forceinline__ void pair_unit(const unsigned short* __restrict__ sh16,
                                          const float* __restrict__ Wl,
                                          int l, float* accrow) {
    const int Jp = l & 31, h2 = l >> 5;
    f32x16 acc = {0.f, 0.f, 0.f, 0.f, 0.f, 0.f, 0.f, 0.f,
                  0.f, 0.f, 0.f, 0.f, 0.f, 0.f, 0.f, 0.f};
    #pragma unroll
    for (int cc = 0; cc < 16; ++cc) {
        int e0;
        if (S == 3)      e0 = (Jp << 8) + (cc << 4) + (h2 << 3);
        else if (S == 5) e0 = ((cc >> 2) << 11) + (Jp << 6) + ((cc & 3) << 4) + (h2 << 3);
        else             e0 = (cc << 9) + (Jp << 4) + (h2 << 3);
        const f16x8 f = *(const f16x8*)&sh16[swz(e0 >> 3) << 3];
        acc = MFMA32(f, f, acc);
    }
    float qa = 0.f, qb = 0.f;
    #pragma unroll
    for (int r2 = 0; r2 < 8; ++r2) {
        const int r = 2 * r2;
        const int J = (r & 3) + 8 * (r >> 2) + 4 * h2;
        const float w = Wl[((J >> 1) << 4) + (Jp >> 1)];
        qa += w * ((Jp & 1) ? acc[r + 1] : acc[r]);
    }
    #pragma unroll
    for (int r = 0; r < 8; ++r) {
        const int J = (r & 3) + 8 * (r >> 2) + 4 * h2;
        const float w = Wl[((J & 15) << 4) + (Jp & 15)];
        qb += w * ((Jp & 16) ? acc[r + 8] : acc[r]);
    }
    qa = wave_sum(qa);
    qb = wave_sum(qb);
    if (l == 0) { atomicAdd(&accrow[S], qa); atomicAdd(&accrow[S + 1], qb); }
}

__device__ __forceinline__ void unit9(const unsigned short* __restrict__ sh16,
                                      const float* __restrict__ Wl,
                                      int i, int h, int l, float* accrow) {
    f32x4 acc = {0.f, 0.f, 0.f, 0.f};
    #pragma unroll
    for (int cc = 0; cc < 16; ++cc) {
        const int e0 = ((4 * cc + h) << 7) + (i << 3);
        const f16x8 f = *(const f16x8*)&sh16[swz(e0 >> 3) << 3];
        acc = MFMAH(f, f, acc);
    }
    contract16(Wl, acc, i, h, l, &accrow[9]);
}

__device__ __forceinline__ void unit10(const unsigned short* __restrict__ sh16,
                                       const float* __restrict__ Wl,
                                       int i, int h, int l, int c0, int c1, float* accrow) {
    f32x4 acc = {0.f, 0.f, 0.f, 0.f};
    #pragma unroll
    for (int cc = c0; cc < c1; ++cc) {
        const int a0 = 8 * cc + 2 * h;
        const int ea = a0 * 64 + 4 * i;
        const int eb = ea + 64;
        Frag fr;
        fr.q[0] = *(const uint2*)&sh16[(swz(ea >> 3) << 3) + (ea & 7)];
        fr.q[1] = *(const uint2*)&sh16[(swz(eb >> 3) << 3) + (eb & 7)];
        acc = MFMAH(fr.v, fr.v, acc);
    }
    contract16(Wl, acc, i, h, l, &accrow[10]);
}

__device__ __forceinline__ void unit11(const unsigned short* __restrict__ sh16,
                                       const float* __restrict__ Wl,
                                       int i, int h, int l, int c0, int c1, float* accrow) {
    f32x4 acc = {0.f, 0.f, 0.f, 0.f};
    #pragma unroll
    for (int cc = c0; cc < c1; ++cc) {
        Frag fr;
        #pragma unroll
        for (int p = 0; p < 4; ++p) {
            const int ap = 16 * cc + 4 * h + p;
            const int e = ap * 32 + 2 * i;
            fr.w[p] = *(const unsigned int*)&sh16[(swz(e >> 3) << 3) + (e & 7)];
        }
        acc = MFMAH(fr.v, fr.v, acc);
    }
    contract16(Wl, acc, i, h, l, &accrow[11]);
}

// ------------------------------ fused main ----------------------------------
// Block remap: blockIdx = (row&7) + 8*(unit + 16*(row>>3)), unit 0..15.
// unit 0..7  -> contiguous tile (seg = unit), s = 3..11 + sumsq
// unit 8..15 -> col-major tile (c0 = (unit-8)*64), s = 0,1,2,12
// All 16 blocks of a row share idx%8 -> same XCD; adjacent dispatch -> the
// col read of the row hits that XCD's L2.
__global__ __launch_bounds__(256, 5) void main_kernel(const float* __restrict__ v,
                                                      const float* __restrict__ ws,
                                                      float* __restrict__ accg) {
    __shared__ unsigned short sh16[8192];   // fp16 tile (both paths, 16 KB)
    __shared__ float Wl[256];
    const int t = threadIdx.x;
    const int l = t & 63, wv = t >> 6;
    const int i = l & 15, h = l >> 4;
    Wl[t] = ws[t];

    const int bi = blockIdx.x;
    const int g = bi >> 3;
    const int unit = g & 15;
    const int row = ((g >> 4) << 3) | (bi & 7);
    float* accrow = &accg[row * 14];

    if (unit < 8) {
        // ---------------- contiguous path: s = 3..11 ----------------
        const int seg = unit;
        const float4* b4 = (const float4*)(v + ((size_t)row << 16) + (seg << 13));

        float ss = 0.f;
        #pragma unroll
        for (int m = 0; m < 8; ++m) {
            const float4 d = b4[m * 256 + t];
            ss = fmaf(d.x, d.x, ss); ss = fmaf(d.y, d.y, ss);
            ss = fmaf(d.z, d.z, ss); ss = fmaf(d.w, d.w, ss);
            H4 p;
            p.h[0] = (_Float16)d.x; p.h[1] = (_Float16)d.y;
            p.h[2] = (_Float16)d.z; p.h[3] = (_Float16)d.w;
            const int e0 = (m * 256 + t) * 4;
            const int idx = (swz(e0 >> 3) << 3) + (e0 & 7);
            *(uint2*)&sh16[idx] = p.q;
        }
        {
            const float s2 = wave_sum(ss);
            if (l == 0) atomicAdd(&accrow[13], s2);
        }
        __syncthreads();

        // static cost-balanced schedule
        if (wv == 0) {
            pair_unit<3>(sh16, Wl, l, accrow);
            unit10(sh16, Wl, i, h, l, 0, 8, accrow);
        } else if (wv == 1) {
            pair_unit<5>(sh16, Wl, l, accrow);
            unit10(sh16, Wl, i, h, l, 8, 16, accrow);
        } else if (wv == 2) {
            pair_unit<7>(sh16, Wl, l, accrow);
            unit11(sh16, Wl, i, h, l, 0, 8, accrow);
        } else {
            unit9(sh16, Wl, i, h, l, accrow);
            unit11(sh16, Wl, i, h, l, 8, 16, accrow);
        }
    } else {
        // ------------- col-major path: s = 0,1,2,12 -------------
        const int c0 = (unit - 8) << 6;
        const float* bp = v + ((size_t)row << 16) + c0 + l;   // lane -> column

        #pragma unroll
        for (int m = 0; m < 8; ++m) {
            const int u0 = 32 * wv + 4 * m;                    // wave covers 32 u's
            H4 p;
            p.h[0] = (_Float16)bp[(u0 + 0) * 512];
            p.h[1] = (_Float16)bp[(u0 + 1) * 512];
            p.h[2] = (_Float16)bp[(u0 + 2) * 512];
            p.h[3] = (_Float16)bp[(u0 + 3) * 512];
            *(uint2*)&sh16[l * 128 + (u0 ^ (8 * (l & 15)))] = p.q;  // b64, conflict-free
        }
        __syncthreads();

        // schedule: w0: s0; w1: s1 + s2[12,16); w2: s2[0,12); w3: s12
        if (wv == 0) {          // s=0: window = u-bits 3..6
            f32x4 acc = {0.f, 0.f, 0.f, 0.f};
            #pragma unroll
            for (int cc = 0; cc < 16; ++cc) {
                const int cl = 4 * cc + h;
                const f16x8 f = *(const f16x8*)&sh16[cl * 128 + ((8 * i) ^ (8 * (cl & 15)))];
                acc = MFMAH(f, f, acc);
            }
            contract16(Wl, acc, i, h, l, &accrow[0]);
        } else if (wv == 1) {   // s=1 full + s=2 tail
            {
                f32x4 acc = {0.f, 0.f, 0.f, 0.f};
                #pragma unroll
                for (int cc = 0; cc < 16; ++cc) {
                    const int cl = 4 * cc + h;
                    const int k = 8 * (cl & 15);
                    Frag fr;
                    fr.q[0] = *(const uint2*)&sh16[cl * 128 + ((4 * i) ^ k)];
                    fr.q[1] = *(const uint2*)&sh16[cl * 128 + ((64 + 4 * i) ^ k)];
                    acc = MFMAH(fr.v, fr.v, acc);
                }
                contract16(Wl, acc, i, h, l, &accrow[1]);
            }
            {
                f32x4 acc = {0.f, 0.f, 0.f, 0.f};
                #pragma unroll
                for (int cc = 12; cc < 16; ++cc) {
                    const int cl = 4 * cc + h;
                    const int k = 8 * (cl & 15);
                    Frag fr;
                    #pragma unroll
                    for (int p = 0; p < 4; ++p)
                        fr.w[p] = *(const unsigned int*)&sh16[cl * 128 + ((2 * i + 32 * p) ^ k)];
                    acc = MFMAH(fr.v, fr.v, acc);
                }
                contract16(Wl, acc, i, h, l, &accrow[2]);
            }
        } else if (wv == 2) {   // s=2 head
            f32x4 acc = {0.f, 0.f, 0.f, 0.f};
            #pragma unroll
            for (int cc = 0; cc < 12; ++cc) {
                const int cl = 4 * cc + h;
                const int k = 8 * (cl & 15);
                Frag fr;
                #pragma unroll
                for (int p = 0; p < 4; ++p)
                    fr.w[p] = *(const unsigned int*)&sh16[cl * 128 + ((2 * i + 32 * p) ^ k)];
                acc = MFMAH(fr.v, fr.v, acc);
            }
            contract16(Wl, acc, i, h, l, &accrow[2]);
        } else {                // s=12: window = col bits 0..3
            f32x4 acc = {0.f, 0.f, 0.f, 0.f};
            #pragma unroll
            for (int cc = 0; cc < 16; ++cc) {
                const int k0 = 32 * cc + 8 * h;
                const int cg = k0 >> 7, u0 = k0 & 127;
                const int col = 16 * cg + i;
                const f16x8 f = *(const f16x8*)&sh16[col * 128 + (u0 ^ (8 * i))];
                acc = MFMAH(f, f, acc);
            }
            contract16(Wl, acc, i, h, l, &accrow[12]);
        }
    }
}

__global__ __launch_bounds__(256) void finalize_kernel(const float* __restrict__ acc,
                                                       float* __restrict__ out) {
    const int idx = blockIdx.x * 256 + threadIdx.x;
    if (idx < 512 * 13) {
        const int row = idx / 13, s = idx % 13;
        out[idx] = acc[row * 14 + s] / acc[row * 14 + 13];
    }
}

extern "C" void kernel_launch(void* const* d_in, const int* in_sizes, int n_in,
                              void* d_out, int out_size, void* d_ws, size_t ws_size,
                              hipStream_t stream) {
    const float* vb = (const float*)d_in[0];
    const float* wt = (const float*)d_in[1];
    float* out = (float*)d_out;
    float* ws = (float*)d_ws;
    float* acc = ws + 256;

    setup_kernel<<<1, 256, 0, stream>>>(wt, ws);
    main_kernel<<<8192, 256, 0, stream>>>(vb, ws, acc);
    finalize_kernel<<<26, 256, 0, stream>>>(acc, out);
}